// Round 1
// baseline (344.813 us; speedup 1.0000x reference)
//
#include <hip/hip_runtime.h>

typedef unsigned short u16;
typedef __bf16 bf16x8 __attribute__((ext_vector_type(8)));
typedef float f32x4 __attribute__((ext_vector_type(4)));

#define S_LEN 2048
#define EMB 1024
#define NH 16
#define HD 64

__device__ __forceinline__ u16 f2bf(float f) {
  union { float f; unsigned u; } v; v.f = f;
  unsigned r = (v.u + 0x7fffu + ((v.u >> 16) & 1u)) >> 16;
  return (u16)r;
}

__device__ __forceinline__ void g2l16(const void* g, void* l) {
  __builtin_amdgcn_global_load_lds(
      (const unsigned int __attribute__((address_space(1)))*)g,
      (unsigned int __attribute__((address_space(3)))*)l, 16, 0, 0);
}

// ---------------- conversion kernels ----------------

__global__ void cvt_bf16(const float* __restrict__ src, u16* __restrict__ dst, int n4) {
  int i = blockIdx.x * blockDim.x + threadIdx.x;
  if (i < n4) {
    float4 f = ((const float4*)src)[i];
    ushort4 o;
    o.x = f2bf(f.x); o.y = f2bf(f.y); o.z = f2bf(f.z); o.w = f2bf(f.w);
    ((ushort4*)dst)[i] = o;
  }
}

// W[K=1024][N=1024] f32 -> Wt[N][K] bf16
__global__ void transcvt(const float* __restrict__ W, u16* __restrict__ Wt) {
  __shared__ float t[32][33];
  int k0 = blockIdx.x * 32, n0 = blockIdx.y * 32;
  int tx = threadIdx.x & 31, ty = threadIdx.x >> 5;  // ty 0..7
#pragma unroll
  for (int i = 0; i < 4; i++) t[ty + i * 8][tx] = W[(k0 + ty + i * 8) * 1024 + n0 + tx];
  __syncthreads();
#pragma unroll
  for (int i = 0; i < 4; i++) Wt[(n0 + ty + i * 8) * 1024 + k0 + tx] = f2bf(t[tx][ty + i * 8]);
}

// bias table: tbl[h][dist] = rel_bias[h][bucket(dist)], dist = q - k >= 0
__global__ void build_bias(const float* __restrict__ rel, float* __restrict__ tbl) {
  int i = blockIdx.x * 256 + threadIdx.x;  // 0..32767
  int h = i >> 11, dist = i & 2047;
  int bk;
  if (dist < 16) {
    bk = dist;
  } else {
    float ls = logf((float)dist * (1.0f / 16.0f)) * (1.0f / logf(8.0f));
    bk = 16 + (int)(ls * 16.0f);
    if (bk > 31) bk = 31;
  }
  tbl[i] = rel[h * 32 + bk];
}

// ---------------- GEMM: C[M,N] = A[M,K] * Bt[N,K]^T ----------------
// MODE 0: bf16 out to [b][h][s][d] (Q/K proj), with scale
// MODE 1: bf16 out to [b][h][d][s] (V transposed)
// MODE 2: f32 out row-major [M][N]

template <int MODE>
__global__ __launch_bounds__(256, 2) void gemm_bf16(const u16* __restrict__ A,
                                                    const u16* __restrict__ Bt,
                                                    void* __restrict__ C, float scale) {
  constexpr int K = EMB;
  __shared__ u16 As[128 * 32];
  __shared__ u16 Bs[128 * 32];
  const int m0 = blockIdx.y * 128;
  const int n0 = blockIdx.x * 128;
  const int tid = threadIdx.x;
  const int lane = tid & 63;
  const int wid = tid >> 6;
  const int wm = (wid >> 1) * 64;
  const int wn = (wid & 1) * 64;
  const int la = lane & 15;
  const int lg = lane >> 4;

  // staging: 16B slot p = tid (instr0), tid+256 (instr1); row = p>>2, slot=(p&3)
  // LDS slot s of row holds global chunk s^(row&3)  -> conflict-free ds_read_b128
  const int r0 = tid >> 2;
  const int c0 = ((tid & 3) ^ (r0 & 3)) * 8;
  const u16* gA = A + (size_t)(m0 + r0) * K + c0;
  const u16* gB = Bt + (size_t)(n0 + r0) * K + c0;
  u16* lA = As + tid * 8;
  u16* lB = Bs + tid * 8;

  f32x4 acc[4][4] = {};

  for (int k0 = 0; k0 < K; k0 += 32) {
    g2l16(gA, lA);
    g2l16(gA + 64 * K, lA + 2048);
    g2l16(gB, lB);
    g2l16(gB + 64 * K, lB + 2048);
    gA += 32;
    gB += 32;
    __syncthreads();
    bf16x8 af[4], bb[4];
#pragma unroll
    for (int mf = 0; mf < 4; mf++) {
      int row = wm + mf * 16 + la;
      af[mf] = *(const bf16x8*)&As[row * 32 + ((lg ^ (row & 3)) << 3)];
    }
#pragma unroll
    for (int nf = 0; nf < 4; nf++) {
      int row = wn + nf * 16 + la;
      bb[nf] = *(const bf16x8*)&Bs[row * 32 + ((lg ^ (row & 3)) << 3)];
    }
#pragma unroll
    for (int mf = 0; mf < 4; mf++)
#pragma unroll
      for (int nf = 0; nf < 4; nf++)
        acc[mf][nf] =
            __builtin_amdgcn_mfma_f32_16x16x32_bf16(af[mf], bb[nf], acc[mf][nf], 0, 0, 0);
    __syncthreads();
  }

#pragma unroll
  for (int mf = 0; mf < 4; mf++)
#pragma unroll
    for (int nf = 0; nf < 4; nf++)
#pragma unroll
      for (int r = 0; r < 4; r++) {
        int m = m0 + wm + mf * 16 + lg * 4 + r;
        int n = n0 + wn + nf * 16 + la;
        float v = acc[mf][nf][r] * scale;
        if constexpr (MODE == 0) {
          int b = m >> 11, s = m & 2047, h = n >> 6, d = n & 63;
          ((u16*)C)[(((size_t)(b * 16 + h) * 2048 + s) << 6) + d] = f2bf(v);
        } else if constexpr (MODE == 1) {
          int b = m >> 11, s = m & 2047, h = n >> 6, d = n & 63;
          ((u16*)C)[(((size_t)(b * 16 + h) * 64 + d) << 11) + s] = f2bf(v);
        } else {
          ((float*)C)[(size_t)m * 1024 + n] = v;
        }
      }
}

// ---------------- flash attention ----------------
// grid (B*H, S/128); 4 waves, each 32 q-rows. K tile [64 kv][64 d], V tile [64 d][64 s].

__global__ __launch_bounds__(256, 2) void attn_kernel(const u16* __restrict__ Qb,
                                                      const u16* __restrict__ Kb,
                                                      const u16* __restrict__ Vtb,
                                                      const float* __restrict__ btbl,
                                                      u16* __restrict__ O) {
  __shared__ u16 Ks[64 * 64];
  __shared__ u16 Vs[64 * 64];
  __shared__ u16 Ps[4][32 * 64];
  __shared__ float bias_s[S_LEN];

  const int bh = blockIdx.x;
  const int h = bh & (NH - 1);
  const int b = bh >> 4;
  const int q0 = blockIdx.y * 128;
  const int tid = threadIdx.x;
  const int lane = tid & 63;
  const int w = tid >> 6;
  const int la = lane & 15;
  const int lg = lane >> 4;

  {
    const float4* src = (const float4*)(btbl + h * S_LEN);
    float4* dst = (float4*)bias_s;
    dst[tid] = src[tid];
    dst[tid + 256] = src[tid + 256];
  }

  const u16* Qg = Qb + (size_t)bh * S_LEN * HD;
  const u16* Kg = Kb + (size_t)bh * S_LEN * HD;
  const u16* Vg = Vtb + (size_t)bh * HD * S_LEN;

  const int qw = q0 + w * 32;
  bf16x8 qf_[2][2];
#pragma unroll
  for (int qf = 0; qf < 2; qf++)
#pragma unroll
    for (int kk = 0; kk < 2; kk++)
      qf_[qf][kk] = *(const bf16x8*)&Qg[(qw + qf * 16 + la) * HD + kk * 32 + lg * 8];

  f32x4 o_acc[2][4] = {};
  float m_run[2][4], l_run[2][4];
#pragma unroll
  for (int qf = 0; qf < 2; qf++)
#pragma unroll
    for (int r = 0; r < 4; r++) {
      m_run[qf][r] = -1e30f;
      l_run[qf][r] = 0.f;
    }

  // staging addr precompute (8 chunks of 16B per 128B row, XOR-swizzled slots)
  const int sr = tid >> 3;  // 0..31
  const int sc8 = tid & 7;
  const int scz = (sc8 ^ (sr & 7)) * 8;
  const u16* KgT = Kg + sr * 64 + scz;
  const u16* VgT = Vg + sr * S_LEN + scz;
  u16* lK = Ks + tid * 8;
  u16* lV = Vs + tid * 8;

  const int kv_end = (S_LEN < q0 + 128) ? S_LEN : (q0 + 128);
  const int qmax = qw + 31;

  for (int kv0 = 0; kv0 < kv_end; kv0 += 64) {
    g2l16(KgT + kv0 * 64, lK);
    g2l16(KgT + kv0 * 64 + 32 * 64, lK + 2048);
    g2l16(VgT + kv0, lV);
    g2l16(VgT + kv0 + 32 * S_LEN, lV + 2048);
    __syncthreads();
    if (kv0 <= qmax) {
      // S = Q K^T
      f32x4 s_acc[2][4] = {};
#pragma unroll
      for (int nf = 0; nf < 4; nf++) {
        int row = nf * 16 + la;
#pragma unroll
        for (int kk = 0; kk < 2; kk++) {
          bf16x8 kfrag = *(const bf16x8*)&Ks[row * 64 + (((kk * 4 + lg) ^ (row & 7)) << 3)];
#pragma unroll
          for (int qf = 0; qf < 2; qf++)
            s_acc[qf][nf] =
                __builtin_amdgcn_mfma_f32_16x16x32_bf16(qf_[qf][kk], kfrag, s_acc[qf][nf], 0, 0, 0);
        }
      }
      // bias + causal mask + online softmax
#pragma unroll
      for (int qf = 0; qf < 2; qf++) {
        float pv[4][4];
#pragma unroll
        for (int nf = 0; nf < 4; nf++) {
          int kv = kv0 + nf * 16 + la;
#pragma unroll
          for (int r = 0; r < 4; r++) {
            int q = qw + qf * 16 + lg * 4 + r;
            float s = s_acc[qf][nf][r];
            pv[nf][r] = (kv <= q) ? (s + bias_s[q - kv]) : -__builtin_inff();
          }
        }
#pragma unroll
        for (int r = 0; r < 4; r++) {
          float m = fmaxf(fmaxf(pv[0][r], pv[1][r]), fmaxf(pv[2][r], pv[3][r]));
          m = fmaxf(m, __shfl_xor(m, 1));
          m = fmaxf(m, __shfl_xor(m, 2));
          m = fmaxf(m, __shfl_xor(m, 4));
          m = fmaxf(m, __shfl_xor(m, 8));
          float mn = fmaxf(m_run[qf][r], m);
          float sc = __expf(m_run[qf][r] - mn);
          m_run[qf][r] = mn;
          float rs = 0.f;
#pragma unroll
          for (int nf = 0; nf < 4; nf++) {
            float p = __expf(pv[nf][r] - mn);
            pv[nf][r] = p;
            rs += p;
          }
          rs += __shfl_xor(rs, 1);
          rs += __shfl_xor(rs, 2);
          rs += __shfl_xor(rs, 4);
          rs += __shfl_xor(rs, 8);
          l_run[qf][r] = l_run[qf][r] * sc + rs;
#pragma unroll
          for (int df = 0; df < 4; df++) o_acc[qf][df][r] *= sc;
        }
        // P -> LDS (swizzled rows of 64 bf16)
#pragma unroll
        for (int nf = 0; nf < 4; nf++)
#pragma unroll
          for (int r = 0; r < 4; r++) {
            int qrow = qf * 16 + lg * 4 + r;
            int kvc = nf * 16 + la;
            Ps[w][qrow * 64 + ((((kvc >> 3) ^ (qrow & 7)) << 3) | (kvc & 7))] = f2bf(pv[nf][r]);
          }
      }
      // O += P V
#pragma unroll
      for (int ks = 0; ks < 2; ks++) {
        bf16x8 pfrag[2];
#pragma unroll
        for (int qf = 0; qf < 2; qf++) {
          int row = qf * 16 + la;
          pfrag[qf] = *(const bf16x8*)&Ps[w][row * 64 + (((ks * 4 + lg) ^ (row & 7)) << 3)];
        }
#pragma unroll
        for (int df = 0; df < 4; df++) {
          int row = df * 16 + la;
          bf16x8 vfrag = *(const bf16x8*)&Vs[row * 64 + (((ks * 4 + lg) ^ (row & 7)) << 3)];
#pragma unroll
          for (int qf = 0; qf < 2; qf++)
            o_acc[qf][df] =
                __builtin_amdgcn_mfma_f32_16x16x32_bf16(pfrag[qf], vfrag, o_acc[qf][df], 0, 0, 0);
        }
      }
    }
    __syncthreads();
  }

#pragma unroll
  for (int qf = 0; qf < 2; qf++)
#pragma unroll
    for (int df = 0; df < 4; df++)
#pragma unroll
      for (int r = 0; r < 4; r++) {
        int s = qw + qf * 16 + lg * 4 + r;
        int col = h * HD + df * 16 + la;
        float v = o_acc[qf][df][r] / l_run[qf][r];
        O[((size_t)(b * S_LEN + s)) * EMB + col] = f2bf(v);
      }
}

// ---------------- host ----------------

extern "C" void kernel_launch(void* const* d_in, const int* in_sizes, int n_in, void* d_out,
                              int out_size, void* d_ws, size_t ws_size, hipStream_t stream) {
  (void)in_sizes; (void)n_in; (void)out_size; (void)ws_size;
  const float* inq = (const float*)d_in[0];
  const float* inkv = (const float*)d_in[1];
  // d_in[2] = mask (causal tril, applied analytically)
  const float* Wq = (const float*)d_in[3];
  const float* Wk = (const float*)d_in[4];
  const float* Wv = (const float*)d_in[5];
  const float* Wo = (const float*)d_in[6];
  const float* rel = (const float*)d_in[7];
  float* out = (float*)d_out;

  char* ws = (char*)d_ws;
  size_t off = 0;
  auto alloc = [&](size_t bytes) {
    void* p = ws + off;
    off += (bytes + 255) & ~(size_t)255;
    return p;
  };
  u16* Aq = (u16*)alloc(16777216);    // inputs_q bf16 [8192][1024]
  u16* Akv = (u16*)alloc(16777216);   // inputs_kv bf16
  u16* Wqt = (u16*)alloc(2097152);    // Wq^T bf16 [N][K]
  u16* Wkt = (u16*)alloc(2097152);
  u16* Wvt = (u16*)alloc(2097152);
  u16* Wot = (u16*)alloc(2097152);
  u16* Qb = (u16*)alloc(16777216);    // Q bf16 [b][h][s][d], pre-scaled 1/8
  u16* Kb = (u16*)alloc(16777216);    // K bf16 [b][h][s][d]
  u16* Vtb = (u16*)alloc(16777216);   // V bf16 [b][h][d][s]
  u16* Ob = (u16*)alloc(16777216);    // attn out bf16 [b][s][h*64+d]
  float* btbl = (float*)alloc(131072);

  cvt_bf16<<<8192, 256, 0, stream>>>(inq, Aq, 2097152);
  cvt_bf16<<<8192, 256, 0, stream>>>(inkv, Akv, 2097152);
  transcvt<<<dim3(32, 32), 256, 0, stream>>>(Wq, Wqt);
  transcvt<<<dim3(32, 32), 256, 0, stream>>>(Wk, Wkt);
  transcvt<<<dim3(32, 32), 256, 0, stream>>>(Wv, Wvt);
  transcvt<<<dim3(32, 32), 256, 0, stream>>>(Wo, Wot);
  build_bias<<<128, 256, 0, stream>>>(rel, btbl);

  gemm_bf16<0><<<dim3(8, 64), 256, 0, stream>>>(Aq, Wqt, Qb, 0.125f);
  gemm_bf16<0><<<dim3(8, 64), 256, 0, stream>>>(Akv, Wkt, Kb, 1.0f);
  gemm_bf16<1><<<dim3(8, 64), 256, 0, stream>>>(Akv, Wvt, Vtb, 1.0f);
  attn_kernel<<<dim3(64, 16), 256, 0, stream>>>(Qb, Kb, Vtb, btbl, Ob);
  gemm_bf16<2><<<dim3(8, 64), 256, 0, stream>>>(Ob, Wot, out, 1.0f);
}

// Round 2
// 243.288 us; speedup vs baseline: 1.4173x; 1.4173x over previous
//
#include <hip/hip_runtime.h>

typedef unsigned short u16;
typedef unsigned int u32;
typedef __bf16 bf16x8 __attribute__((ext_vector_type(8)));
typedef float f32x4 __attribute__((ext_vector_type(4)));
typedef float f32x16 __attribute__((ext_vector_type(16)));

#define S_LEN 2048
#define EMB 1024
#define NH 16
#define HD 64
#define LOG2E 1.44269504088896f

__device__ __forceinline__ u16 f2bf(float f) {
  union { float f; unsigned u; } v; v.f = f;
  unsigned r = (v.u + 0x7fffu + ((v.u >> 16) & 1u)) >> 16;
  return (u16)r;
}

__device__ __forceinline__ u32 packbf(float a, float b) {
  union { __bf16 h[2]; u32 u; } x;
  x.h[0] = (__bf16)a; x.h[1] = (__bf16)b;
  return x.u;
}

__device__ __forceinline__ void g2l16(const void* g, void* l) {
  __builtin_amdgcn_global_load_lds(
      (const unsigned int __attribute__((address_space(1)))*)g,
      (unsigned int __attribute__((address_space(3)))*)l, 16, 0, 0);
}

// ---------------- conversion kernels ----------------

__global__ void cvt_bf16(const float* __restrict__ src, u16* __restrict__ dst, int n4) {
  int i = blockIdx.x * blockDim.x + threadIdx.x;
  if (i < n4) {
    float4 f = ((const float4*)src)[i];
    ushort4 o;
    o.x = f2bf(f.x); o.y = f2bf(f.y); o.z = f2bf(f.z); o.w = f2bf(f.w);
    ((ushort4*)dst)[i] = o;
  }
}

// W[K=1024][N=1024] f32 -> Wt[N][K] bf16
__global__ void transcvt(const float* __restrict__ W, u16* __restrict__ Wt) {
  __shared__ float t[32][33];
  int k0 = blockIdx.x * 32, n0 = blockIdx.y * 32;
  int tx = threadIdx.x & 31, ty = threadIdx.x >> 5;  // ty 0..7
#pragma unroll
  for (int i = 0; i < 4; i++) t[ty + i * 8][tx] = W[(k0 + ty + i * 8) * 1024 + n0 + tx];
  __syncthreads();
#pragma unroll
  for (int i = 0; i < 4; i++) Wt[(n0 + ty + i * 8) * 1024 + k0 + tx] = f2bf(t[tx][ty + i * 8]);
}

// bias table: tbl[h][dist] = rel_bias[h][bucket(dist)], dist = q - k >= 0
__global__ void build_bias(const float* __restrict__ rel, float* __restrict__ tbl) {
  int i = blockIdx.x * 256 + threadIdx.x;  // 0..32767
  int h = i >> 11, dist = i & 2047;
  int bk;
  if (dist < 16) {
    bk = dist;
  } else {
    float ls = logf((float)dist * (1.0f / 16.0f)) * (1.0f / logf(8.0f));
    bk = 16 + (int)(ls * 16.0f);
    if (bk > 31) bk = 31;
  }
  tbl[i] = rel[h * 32 + bk];
}

// ---------------- GEMM: C[M,N] = A[M,K] * Bt[N,K]^T ----------------
// MODE 0: bf16 out to [b][h][s][d] (Q/K proj), with scale
// MODE 1: bf16 out to [b][h][d][s] (V transposed)
// MODE 2: f32 out row-major [M][N]

template <int MODE>
__global__ __launch_bounds__(256, 2) void gemm_bf16(const u16* __restrict__ A,
                                                    const u16* __restrict__ Bt,
                                                    void* __restrict__ C, float scale) {
  constexpr int K = EMB;
  __shared__ u16 As[128 * 32];
  __shared__ u16 Bs[128 * 32];
  const int m0 = blockIdx.y * 128;
  const int n0 = blockIdx.x * 128;
  const int tid = threadIdx.x;
  const int lane = tid & 63;
  const int wid = tid >> 6;
  const int wm = (wid >> 1) * 64;
  const int wn = (wid & 1) * 64;
  const int la = lane & 15;
  const int lg = lane >> 4;

  const int r0 = tid >> 2;
  const int c0 = ((tid & 3) ^ (r0 & 3)) * 8;
  const u16* gA = A + (size_t)(m0 + r0) * K + c0;
  const u16* gB = Bt + (size_t)(n0 + r0) * K + c0;
  u16* lA = As + tid * 8;
  u16* lB = Bs + tid * 8;

  f32x4 acc[4][4] = {};

  for (int k0 = 0; k0 < K; k0 += 32) {
    g2l16(gA, lA);
    g2l16(gA + 64 * K, lA + 2048);
    g2l16(gB, lB);
    g2l16(gB + 64 * K, lB + 2048);
    gA += 32;
    gB += 32;
    __syncthreads();
    bf16x8 af[4], bb[4];
#pragma unroll
    for (int mf = 0; mf < 4; mf++) {
      int row = wm + mf * 16 + la;
      af[mf] = *(const bf16x8*)&As[row * 32 + ((lg ^ (row & 3)) << 3)];
    }
#pragma unroll
    for (int nf = 0; nf < 4; nf++) {
      int row = wn + nf * 16 + la;
      bb[nf] = *(const bf16x8*)&Bs[row * 32 + ((lg ^ (row & 3)) << 3)];
    }
#pragma unroll
    for (int mf = 0; mf < 4; mf++)
#pragma unroll
      for (int nf = 0; nf < 4; nf++)
        acc[mf][nf] =
            __builtin_amdgcn_mfma_f32_16x16x32_bf16(af[mf], bb[nf], acc[mf][nf], 0, 0, 0);
    __syncthreads();
  }

#pragma unroll
  for (int mf = 0; mf < 4; mf++)
#pragma unroll
    for (int nf = 0; nf < 4; nf++)
#pragma unroll
      for (int r = 0; r < 4; r++) {
        int m = m0 + wm + mf * 16 + lg * 4 + r;
        int n = n0 + wn + nf * 16 + la;
        float v = acc[mf][nf][r] * scale;
        if constexpr (MODE == 0) {
          int b = m >> 11, s = m & 2047, h = n >> 6, d = n & 63;
          ((u16*)C)[(((size_t)(b * 16 + h) * 2048 + s) << 6) + d] = f2bf(v);
        } else if constexpr (MODE == 1) {
          int b = m >> 11, s = m & 2047, h = n >> 6, d = n & 63;
          ((u16*)C)[(((size_t)(b * 16 + h) * 64 + d) << 11) + s] = f2bf(v);
        } else {
          ((float*)C)[(size_t)m * 1024 + n] = v;
        }
      }
}

// ---------------- flash attention, swapped-QK^T (m214 structure) ----------------
// grid (B*H, 16); block 256 = 4 waves x 32 q-rows; 32x32x16 MFMA; KVBLK=64.
// S^T = mfma(K, Q): lane holds 32 kv-scores of one q-row -> in-register softmax.
// O^T = mfma(V^T, P^T): rescale factors stay per-lane scalars.

__global__ __launch_bounds__(256, 2) void attn_kernel(const u16* __restrict__ Qb,
                                                      const u16* __restrict__ Kb,
                                                      const u16* __restrict__ Vtb,
                                                      const float* __restrict__ btbl,
                                                      u16* __restrict__ O) {
  __shared__ u16 Ks[64 * 64];
  __shared__ u16 Vs[64 * 64];
  __shared__ float bias_s[S_LEN];

  const int bh = blockIdx.x;
  const int h = bh & (NH - 1);
  const int b = bh >> 4;
  const int qt = 15 - blockIdx.y;  // heavy tiles dispatch first
  const int q0 = qt * 128;
  const int tid = threadIdx.x;
  const int lane = tid & 63;
  const int w = tid >> 6;
  const int la = lane & 31;
  const int hi = lane >> 5;

  {
    const float4* src = (const float4*)(btbl + h * S_LEN);
    float4* dst = (float4*)bias_s;
    dst[tid] = src[tid];
    dst[tid + 256] = src[tid + 256];
  }

  const u16* Qg = Qb + (size_t)bh * S_LEN * HD;
  const u16* Kg = Kb + (size_t)bh * S_LEN * HD;
  const u16* Vg = Vtb + (size_t)bh * HD * S_LEN;

  const int qw = q0 + w * 32;
  const int q = qw + la;  // this lane's q-row (both halves share q)

  bf16x8 qfrag[4];
#pragma unroll
  for (int kk = 0; kk < 4; kk++)
    qfrag[kk] = *(const bf16x8*)&Qg[(size_t)q * HD + kk * 16 + hi * 8];

  f32x16 oacc[2] = {};
  float mrun = -1e30f;
  float lrun = 0.f;

  // staging: 64x64 bf16 tile = 512 x16B chunks; slot c of row r holds global chunk c^(r&7)
  const int sr = tid >> 3;
  const int scz = ((tid & 7) ^ (sr & 7)) * 8;
  const u16* KgT = Kg + sr * 64 + scz;
  const u16* VgT = Vg + (size_t)sr * S_LEN + scz;
  u16* lK = Ks + tid * 8;
  u16* lV = Vs + tid * 8;

  const int nt = (q0 + 128) >> 6;
  const int qmax = qw + 31;

  for (int t = 0; t < nt; t++) {
    const int kv0 = t << 6;
    g2l16(KgT + kv0 * 64, lK);
    g2l16(KgT + kv0 * 64 + 32 * 64, lK + 2048);
    g2l16(VgT + kv0, lV);
    g2l16(VgT + kv0 + 32 * S_LEN, lV + 2048);
    __syncthreads();
    if (kv0 <= qmax) {
      // ---- S^T = K Q^T ----
      f32x16 sacc[2] = {};
      __builtin_amdgcn_s_setprio(1);
#pragma unroll
      for (int kk = 0; kk < 4; kk++) {
#pragma unroll
        for (int nf = 0; nf < 2; nf++) {
          int row = nf * 32 + la;
          bf16x8 kf = *(const bf16x8*)&Ks[row * 64 + (((kk * 2 + hi) ^ (row & 7)) << 3)];
          sacc[nf] = __builtin_amdgcn_mfma_f32_32x32x16_bf16(kf, qfrag[kk], sacc[nf], 0, 0, 0);
        }
      }
      __builtin_amdgcn_s_setprio(0);

      // ---- bias + causal mask ----
      float pf[32];
      const bool full = (kv0 + 63 <= qw);
#pragma unroll
      for (int nf = 0; nf < 2; nf++)
#pragma unroll
        for (int r = 0; r < 16; r++) {
          int kv = kv0 + nf * 32 + (r & 3) + ((r >> 2) << 3) + hi * 4;
          int bi = q - kv;
          if (bi < 0) bi = 0;
          float sb = sacc[nf][r] + bias_s[bi];
          if (!full) sb = (kv <= q) ? sb : -1e30f;
          pf[nf * 16 + r] = sb;
        }

      // ---- online softmax (in-register row reduce + one half-swap) ----
      float tm[16];
#pragma unroll
      for (int i = 0; i < 16; i++) tm[i] = fmaxf(pf[i], pf[i + 16]);
#pragma unroll
      for (int i = 0; i < 8; i++) tm[i] = fmaxf(tm[i], tm[i + 8]);
#pragma unroll
      for (int i = 0; i < 4; i++) tm[i] = fmaxf(tm[i], tm[i + 4]);
      float mt = fmaxf(fmaxf(tm[0], tm[1]), fmaxf(tm[2], tm[3]));
      mt = fmaxf(mt, __shfl_xor(mt, 32));
      float mn = fmaxf(mrun, mt);
      float sc = exp2f((mrun - mn) * LOG2E);
      mrun = mn;
      float mnl = mn * LOG2E;
      float ts[16];
#pragma unroll
      for (int i = 0; i < 16; i++) {
        float p0 = exp2f(fmaf(pf[i], LOG2E, -mnl));
        float p1 = exp2f(fmaf(pf[i + 16], LOG2E, -mnl));
        pf[i] = p0;
        pf[i + 16] = p1;
        ts[i] = p0 + p1;
      }
#pragma unroll
      for (int i = 0; i < 8; i++) ts[i] += ts[i + 8];
#pragma unroll
      for (int i = 0; i < 4; i++) ts[i] += ts[i + 4];
      float rs = (ts[0] + ts[1]) + (ts[2] + ts[3]);
      rs += __shfl_xor(rs, 32);
      lrun = lrun * sc + rs;
#pragma unroll
      for (int d2 = 0; d2 < 2; d2++)
#pragma unroll
        for (int r = 0; r < 16; r++) oacc[d2][r] *= sc;

      // ---- repack P^T into PV B-fragments (pair-pack + half-swap) ----
      // pa[ks] lane(la,hi): P[q=qw+la][kv = kv0 + ks*16 + hi*8 + 0..7]
      u32 paw[4][4];
#pragma unroll
      for (int ks = 0; ks < 4; ks++) {
        const int nf = ks >> 1;
        const int e80 = (ks & 1) * 2;
#pragma unroll
        for (int half = 0; half < 2; half++) {
          u32 Y0 = packbf(pf[nf * 16 + 4 * e80 + 2 * half], pf[nf * 16 + 4 * e80 + 2 * half + 1]);
          u32 Y1 = packbf(pf[nf * 16 + 4 * (e80 + 1) + 2 * half],
                          pf[nf * 16 + 4 * (e80 + 1) + 2 * half + 1]);
          u32 Y0s = (u32)__shfl_xor((int)Y0, 32);
          u32 Y1s = (u32)__shfl_xor((int)Y1, 32);
          paw[ks][half] = hi ? Y1s : Y0;
          paw[ks][2 + half] = hi ? Y1 : Y0s;
        }
      }

      // ---- O^T += V^T P^T ----
      __builtin_amdgcn_s_setprio(1);
#pragma unroll
      for (int d2 = 0; d2 < 2; d2++) {
#pragma unroll
        for (int ks = 0; ks < 4; ks++) {
          int row = d2 * 32 + la;
          bf16x8 vf = *(const bf16x8*)&Vs[row * 64 + (((ks * 2 + hi) ^ (row & 7)) << 3)];
          union { u32 w[4]; bf16x8 v; } pu;
          pu.w[0] = paw[ks][0]; pu.w[1] = paw[ks][1];
          pu.w[2] = paw[ks][2]; pu.w[3] = paw[ks][3];
          oacc[d2] = __builtin_amdgcn_mfma_f32_32x32x16_bf16(vf, pu.v, oacc[d2], 0, 0, 0);
        }
      }
      __builtin_amdgcn_s_setprio(0);
    }
    __syncthreads();
  }

  // ---- epilogue: O[q][d] = oacc^T / l ----
  const float inv = 1.0f / lrun;
  u16* Og = O + ((size_t)(b * S_LEN + q)) * EMB + h * HD;
#pragma unroll
  for (int d2 = 0; d2 < 2; d2++)
#pragma unroll
    for (int g = 0; g < 4; g++) {
      ushort4 ov;
      ov.x = f2bf(oacc[d2][g * 4 + 0] * inv);
      ov.y = f2bf(oacc[d2][g * 4 + 1] * inv);
      ov.z = f2bf(oacc[d2][g * 4 + 2] * inv);
      ov.w = f2bf(oacc[d2][g * 4 + 3] * inv);
      *(ushort4*)&Og[d2 * 32 + g * 8 + hi * 4] = ov;
    }
}

// ---------------- host ----------------

extern "C" void kernel_launch(void* const* d_in, const int* in_sizes, int n_in, void* d_out,
                              int out_size, void* d_ws, size_t ws_size, hipStream_t stream) {
  (void)in_sizes; (void)n_in; (void)out_size; (void)ws_size;
  const float* inq = (const float*)d_in[0];
  const float* inkv = (const float*)d_in[1];
  // d_in[2] = mask (causal tril, applied analytically)
  const float* Wq = (const float*)d_in[3];
  const float* Wk = (const float*)d_in[4];
  const float* Wv = (const float*)d_in[5];
  const float* Wo = (const float*)d_in[6];
  const float* rel = (const float*)d_in[7];
  float* out = (float*)d_out;

  char* ws = (char*)d_ws;
  size_t off = 0;
  auto alloc = [&](size_t bytes) {
    void* p = ws + off;
    off += (bytes + 255) & ~(size_t)255;
    return p;
  };
  u16* Aq = (u16*)alloc(16777216);    // inputs_q bf16 [8192][1024]
  u16* Akv = (u16*)alloc(16777216);   // inputs_kv bf16
  u16* Wqt = (u16*)alloc(2097152);    // Wq^T bf16 [N][K]
  u16* Wkt = (u16*)alloc(2097152);
  u16* Wvt = (u16*)alloc(2097152);
  u16* Wot = (u16*)alloc(2097152);
  u16* Qb = (u16*)alloc(16777216);    // Q bf16 [b][h][s][d], pre-scaled 1/8
  u16* Kb = (u16*)alloc(16777216);    // K bf16 [b][h][s][d]
  u16* Vtb = (u16*)alloc(16777216);   // V bf16 [b][h][d][s]
  u16* Ob = (u16*)alloc(16777216);    // attn out bf16 [b][s][h*64+d]
  float* btbl = (float*)alloc(131072);

  cvt_bf16<<<8192, 256, 0, stream>>>(inq, Aq, 2097152);
  cvt_bf16<<<8192, 256, 0, stream>>>(inkv, Akv, 2097152);
  transcvt<<<dim3(32, 32), 256, 0, stream>>>(Wq, Wqt);
  transcvt<<<dim3(32, 32), 256, 0, stream>>>(Wk, Wkt);
  transcvt<<<dim3(32, 32), 256, 0, stream>>>(Wv, Wvt);
  transcvt<<<dim3(32, 32), 256, 0, stream>>>(Wo, Wot);
  build_bias<<<128, 256, 0, stream>>>(rel, btbl);

  gemm_bf16<0><<<dim3(8, 64), 256, 0, stream>>>(Aq, Wqt, Qb, 0.125f);
  gemm_bf16<0><<<dim3(8, 64), 256, 0, stream>>>(Akv, Wkt, Kb, 1.0f);
  gemm_bf16<1><<<dim3(8, 64), 256, 0, stream>>>(Akv, Wvt, Vtb, 1.0f);
  attn_kernel<<<dim3(64, 16), 256, 0, stream>>>(Qb, Kb, Vtb, btbl, Ob);
  gemm_bf16<2><<<dim3(8, 64), 256, 0, stream>>>(Ob, Wot, out, 1.0f);
}

// Round 3
// 225.782 us; speedup vs baseline: 1.5272x; 1.0775x over previous
//
#include <hip/hip_runtime.h>

typedef unsigned short u16;
typedef unsigned int u32;
typedef __bf16 bf16x8 __attribute__((ext_vector_type(8)));
typedef float f32x4 __attribute__((ext_vector_type(4)));
typedef float f32x16 __attribute__((ext_vector_type(16)));

#define S_LEN 2048
#define EMB 1024
#define NH 16
#define HD 64
#define LOG2E 1.44269504088896f

__device__ __forceinline__ u16 f2bf(float f) {
  union { float f; unsigned u; } v; v.f = f;
  unsigned r = (v.u + 0x7fffu + ((v.u >> 16) & 1u)) >> 16;
  return (u16)r;
}

__device__ __forceinline__ u32 packbf(float a, float b) {
  union { __bf16 h[2]; u32 u; } x;
  x.h[0] = (__bf16)a; x.h[1] = (__bf16)b;
  return x.u;
}

__device__ __forceinline__ void g2l16(const void* g, void* l) {
  __builtin_amdgcn_global_load_lds(
      (const unsigned int __attribute__((address_space(1)))*)g,
      (unsigned int __attribute__((address_space(3)))*)l, 16, 0, 0);
}

// {x,y} = permlane32_swap(a,b): x=[a.lo,b.lo], y=[a.hi,b.hi] (lane i<->i+32 exchange)
__device__ __forceinline__ void permswap_f(float a, float b, float& x, float& y) {
  auto r = __builtin_amdgcn_permlane32_swap(__float_as_int(a), __float_as_int(b), false, false);
  x = __int_as_float(r[0]);
  y = __int_as_float(r[1]);
}

// ---------------- conversion kernels ----------------

__global__ void cvt_bf16(const float* __restrict__ src, u16* __restrict__ dst, int n4) {
  int i = blockIdx.x * blockDim.x + threadIdx.x;
  if (i < n4) {
    float4 f = ((const float4*)src)[i];
    ushort4 o;
    o.x = f2bf(f.x); o.y = f2bf(f.y); o.z = f2bf(f.z); o.w = f2bf(f.w);
    ((ushort4*)dst)[i] = o;
  }
}

// W[K=1024][N=1024] f32 -> Wt[N][K] bf16
__global__ void transcvt(const float* __restrict__ W, u16* __restrict__ Wt) {
  __shared__ float t[32][33];
  int k0 = blockIdx.x * 32, n0 = blockIdx.y * 32;
  int tx = threadIdx.x & 31, ty = threadIdx.x >> 5;  // ty 0..7
#pragma unroll
  for (int i = 0; i < 4; i++) t[ty + i * 8][tx] = W[(k0 + ty + i * 8) * 1024 + n0 + tx];
  __syncthreads();
#pragma unroll
  for (int i = 0; i < 4; i++) Wt[(n0 + ty + i * 8) * 1024 + k0 + tx] = f2bf(t[tx][ty + i * 8]);
}

// bias table: tbl[h][dist] = rel_bias[h][bucket(dist)], dist = q - k >= 0
__global__ void build_bias(const float* __restrict__ rel, float* __restrict__ tbl) {
  int i = blockIdx.x * 256 + threadIdx.x;  // 0..32767
  int h = i >> 11, dist = i & 2047;
  int bk;
  if (dist < 16) {
    bk = dist;
  } else {
    float ls = logf((float)dist * (1.0f / 16.0f)) * (1.0f / logf(8.0f));
    bk = 16 + (int)(ls * 16.0f);
    if (bk > 31) bk = 31;
  }
  tbl[i] = rel[h * 32 + bk];
}

// ---------------- GEMM: C[M,N] = A[M,K] * Bt[N,K]^T ----------------
// 128x128 tile, BK=32, double-buffered LDS with counted vmcnt (T3/T4-lite).
// MODE 0: bf16 out to [b][h][s][d] (Q/K proj), with scale
// MODE 1: bf16 out to [b][h][d][s] (V transposed)
// MODE 2: f32 out row-major [M][N]

template <int MODE>
__global__ __launch_bounds__(256, 2) void gemm_bf16(const u16* __restrict__ A,
                                                    const u16* __restrict__ Bt,
                                                    void* __restrict__ C, float scale) {
  constexpr int K = EMB;
  __shared__ u16 As[2][128 * 32];
  __shared__ u16 Bs[2][128 * 32];
  const int m0 = blockIdx.y * 128;
  const int n0 = blockIdx.x * 128;
  const int tid = threadIdx.x;
  const int lane = tid & 63;
  const int wid = tid >> 6;
  const int wm = (wid >> 1) * 64;
  const int wn = (wid & 1) * 64;
  const int la = lane & 15;
  const int lg = lane >> 4;

  // staging: LDS slot s of row r holds global chunk s^(r&3) -> conflict-free ds_read_b128
  const int r0 = tid >> 2;
  const int c0 = ((tid & 3) ^ (r0 & 3)) * 8;
  const u16* gA = A + (size_t)(m0 + r0) * K + c0;
  const u16* gB = Bt + (size_t)(n0 + r0) * K + c0;

  f32x4 acc[4][4] = {};

  // prologue: stage K-step 0 into buf 0
  g2l16(gA, As[0] + tid * 8);
  g2l16(gA + 64 * K, As[0] + tid * 8 + 2048);
  g2l16(gB, Bs[0] + tid * 8);
  g2l16(gB + 64 * K, Bs[0] + tid * 8 + 2048);
  gA += 32;
  gB += 32;

  for (int t = 0; t < 32; ++t) {
    const int cur = t & 1;
    if (t < 31) {
      u16* lA = As[cur ^ 1] + tid * 8;
      u16* lB = Bs[cur ^ 1] + tid * 8;
      g2l16(gA, lA);
      g2l16(gA + 64 * K, lA + 2048);
      g2l16(gB, lB);
      g2l16(gB + 64 * K, lB + 2048);
      gA += 32;
      gB += 32;
      asm volatile("s_waitcnt vmcnt(4)" ::: "memory");  // tile t resident, t+1 in flight
    } else {
      asm volatile("s_waitcnt vmcnt(0)" ::: "memory");
    }
    __builtin_amdgcn_s_barrier();
    asm volatile("" ::: "memory");

    bf16x8 af[4], bb[4];
#pragma unroll
    for (int mf = 0; mf < 4; mf++) {
      int row = wm + mf * 16 + la;
      af[mf] = *(const bf16x8*)&As[cur][row * 32 + ((lg ^ (row & 3)) << 3)];
    }
#pragma unroll
    for (int nf = 0; nf < 4; nf++) {
      int row = wn + nf * 16 + la;
      bb[nf] = *(const bf16x8*)&Bs[cur][row * 32 + ((lg ^ (row & 3)) << 3)];
    }
#pragma unroll
    for (int mf = 0; mf < 4; mf++)
#pragma unroll
      for (int nf = 0; nf < 4; nf++)
        acc[mf][nf] =
            __builtin_amdgcn_mfma_f32_16x16x32_bf16(af[mf], bb[nf], acc[mf][nf], 0, 0, 0);

    asm volatile("" ::: "memory");
    __builtin_amdgcn_s_barrier();
    asm volatile("" ::: "memory");
  }

#pragma unroll
  for (int mf = 0; mf < 4; mf++)
#pragma unroll
    for (int nf = 0; nf < 4; nf++)
#pragma unroll
      for (int r = 0; r < 4; r++) {
        int m = m0 + wm + mf * 16 + lg * 4 + r;
        int n = n0 + wn + nf * 16 + la;
        float v = acc[mf][nf][r] * scale;
        if constexpr (MODE == 0) {
          int b = m >> 11, s = m & 2047, h = n >> 6, d = n & 63;
          ((u16*)C)[(((size_t)(b * 16 + h) * 2048 + s) << 6) + d] = f2bf(v);
        } else if constexpr (MODE == 1) {
          int b = m >> 11, s = m & 2047, h = n >> 6, d = n & 63;
          ((u16*)C)[(((size_t)(b * 16 + h) * 64 + d) << 11) + s] = f2bf(v);
        } else {
          ((float*)C)[(size_t)m * 1024 + n] = v;
        }
      }
}

// ---------------- flash attention, swapped-QK^T + VALU diet ----------------
// grid (B*H, 16); block 256 = 4 waves x 32 q-rows; 32x32x16 MFMA; KVBLK=64.
// S^T = mfma(K, Q): lane holds 32 kv-scores of one q-row -> in-register softmax.
// O^T = mfma(V^T, P^T). Tile classes: FAR (bucket-31 uniform bias, no mask),
// NEAR-full (LDS bias, no mask), DIAG (bias+mask). Defer-max THR=8.

__global__ __launch_bounds__(256, 2) void attn_kernel(const u16* __restrict__ Qb,
                                                      const u16* __restrict__ Kb,
                                                      const u16* __restrict__ Vtb,
                                                      const float* __restrict__ btbl,
                                                      u16* __restrict__ O) {
  __shared__ u16 Ks[2][64 * 64];
  __shared__ u16 Vs[2][64 * 64];
  __shared__ float bias_s[S_LEN];

  const int bh = blockIdx.x;
  const int h = bh & (NH - 1);
  const int b = bh >> 4;
  const int qt = 15 - blockIdx.y;  // heavy tiles dispatch first
  const int q0 = qt * 128;
  const int tid = threadIdx.x;
  const int lane = tid & 63;
  const int w = tid >> 6;
  const int la = lane & 31;
  const int hi = lane >> 5;

  {
    const float4* src = (const float4*)(btbl + h * S_LEN);
    float4* dst = (float4*)bias_s;
    dst[tid] = src[tid];
    dst[tid + 256] = src[tid + 256];
  }

  const u16* Qg = Qb + (size_t)bh * S_LEN * HD;
  const u16* Kg = Kb + (size_t)bh * S_LEN * HD;
  const u16* Vg = Vtb + (size_t)bh * HD * S_LEN;

  const int qw = q0 + w * 32;
  const int q = qw + la;  // this lane's q-row (both halves share q)

  bf16x8 qfrag[4];
#pragma unroll
  for (int kk = 0; kk < 4; kk++)
    qfrag[kk] = *(const bf16x8*)&Qg[(size_t)q * HD + kk * 16 + hi * 8];

  f32x16 oacc[2] = {};
  float mrun = -1e30f;
  float lrun = 0.f;

  // staging: 64x64 bf16 tile = 512 x16B chunks; slot c of row r holds global chunk c^(r&7)
  const int sr = tid >> 3;
  const int scz = ((tid & 7) ^ (sr & 7)) * 8;
  const u16* kp = Kg + sr * 64 + scz;
  const u16* vp = Vg + (size_t)sr * S_LEN + scz;

  const int ntblk = (q0 + 128) >> 6;
  const int qmax = qw + 31;

  // prologue: stage tile 0 into buf 0; full-drain sync (also covers bias_s writes)
  g2l16(kp, Ks[0] + tid * 8);
  g2l16(kp + 32 * 64, Ks[0] + tid * 8 + 2048);
  g2l16(vp, Vs[0] + tid * 8);
  g2l16(vp + 32 * S_LEN, Vs[0] + tid * 8 + 2048);
  kp += 4096;
  vp += 64;
  __syncthreads();

  const float bias31 = bias_s[S_LEN - 1];  // bucket 31 (all dist >= 113)

  for (int t = 0; t < ntblk; ++t) {
    const int cur = t & 1;
    if (t + 1 < ntblk) {
      u16* lK = Ks[cur ^ 1] + tid * 8;
      u16* lV = Vs[cur ^ 1] + tid * 8;
      g2l16(kp, lK);
      g2l16(kp + 32 * 64, lK + 2048);
      g2l16(vp, lV);
      g2l16(vp + 32 * S_LEN, lV + 2048);
      kp += 4096;
      vp += 64;
      asm volatile("s_waitcnt vmcnt(4)" ::: "memory");
    } else {
      asm volatile("s_waitcnt vmcnt(0)" ::: "memory");
    }
    __builtin_amdgcn_s_barrier();
    asm volatile("" ::: "memory");

    const int kv0 = t << 6;
    if (kv0 <= qmax) {
      // ---- S^T = K Q^T ----
      f32x16 sacc[2] = {};
      __builtin_amdgcn_s_setprio(1);
#pragma unroll
      for (int kk = 0; kk < 4; kk++) {
#pragma unroll
        for (int nf = 0; nf < 2; nf++) {
          int row = nf * 32 + la;
          bf16x8 kf = *(const bf16x8*)&Ks[cur][row * 64 + (((kk * 2 + hi) ^ (row & 7)) << 3)];
          sacc[nf] = __builtin_amdgcn_mfma_f32_32x32x16_bf16(kf, qfrag[kk], sacc[nf], 0, 0, 0);
        }
      }
      __builtin_amdgcn_s_setprio(0);

      // ---- bias + causal mask (3 tile classes) ----
      float pf[32];
      float adde = 0.f;
      if (kv0 + 176 <= qw) {  // FAR: all distances >= 113 -> bucket 31, uniform bias
#pragma unroll
        for (int nf = 0; nf < 2; nf++)
#pragma unroll
          for (int r = 0; r < 16; r++) pf[nf * 16 + r] = sacc[nf][r];
        adde = bias31;
      } else {
        const int qb2 = q - kv0 - 4 * hi;
        const float* bp = bias_s + (qb2 - 59);  // compile-time ds offsets 4*(59-C)
        if (kv0 + 63 <= qw) {  // NEAR-full: bias varies, no mask/clamp needed
#pragma unroll
          for (int nf = 0; nf < 2; nf++)
#pragma unroll
            for (int r = 0; r < 16; r++) {
              const int Cn = nf * 32 + (r & 3) + ((r >> 2) << 3);
              pf[nf * 16 + r] = sacc[nf][r] + bp[59 - Cn];
            }
        } else {  // DIAG: mask; garbage bias reads are masked out
#pragma unroll
          for (int nf = 0; nf < 2; nf++)
#pragma unroll
            for (int r = 0; r < 16; r++) {
              const int Cn = nf * 32 + (r & 3) + ((r >> 2) << 3);
              pf[nf * 16 + r] = (Cn <= qb2) ? (sacc[nf][r] + bp[59 - Cn]) : -1e30f;
            }
        }
      }

      // ---- tile max (max3 tree) + cross-half via permlane ----
      float a[11];
#pragma unroll
      for (int i = 0; i < 10; i++)
        a[i] = fmaxf(fmaxf(pf[3 * i], pf[3 * i + 1]), pf[3 * i + 2]);
      a[10] = fmaxf(pf[30], pf[31]);
      float b0 = fmaxf(fmaxf(a[0], a[1]), a[2]);
      float b1 = fmaxf(fmaxf(a[3], a[4]), a[5]);
      float b2 = fmaxf(fmaxf(a[6], a[7]), a[8]);
      float b3 = fmaxf(a[9], a[10]);
      float mt = fmaxf(fmaxf(b0, b1), fmaxf(b2, b3)) + adde;
      {
        float x, y;
        permswap_f(mt, mt, x, y);
        mt = fmaxf(x, y);
      }

      // ---- defer-max (T13): rescale only when tile max exceeds running max + 8 ----
      if (__any(mt > mrun + 8.0f)) {
        float mn = fmaxf(mrun, mt);
        float sc = exp2f((mrun - mn) * LOG2E);
        mrun = mn;
        lrun *= sc;
        oacc[0] *= sc;
        oacc[1] *= sc;
      }
      const float ec = (adde - mrun) * LOG2E;

      // ---- exp + row sum ----
      float ps[16];
#pragma unroll
      for (int i = 0; i < 16; i++) {
        float p0 = exp2f(fmaf(pf[i], LOG2E, ec));
        float p1 = exp2f(fmaf(pf[i + 16], LOG2E, ec));
        pf[i] = p0;
        pf[i + 16] = p1;
        ps[i] = p0 + p1;
      }
#pragma unroll
      for (int i = 0; i < 8; i++) ps[i] += ps[i + 8];
#pragma unroll
      for (int i = 0; i < 4; i++) ps[i] += ps[i + 4];
      float rs = (ps[0] + ps[1]) + (ps[2] + ps[3]);
      {
        float x, y;
        permswap_f(rs, rs, x, y);
        rs = x + y;
      }
      lrun += rs;

      // ---- repack P^T into PV B-fragments (cvt_pk pairs + permlane32_swap) ----
      u32 paw[4][4];
#pragma unroll
      for (int ks = 0; ks < 4; ks++) {
        const int nf = ks >> 1;
        const int e80 = (ks & 1) * 2;
#pragma unroll
        for (int half = 0; half < 2; half++) {
          u32 Y0 = packbf(pf[nf * 16 + 4 * e80 + 2 * half], pf[nf * 16 + 4 * e80 + 2 * half + 1]);
          u32 Y1 = packbf(pf[nf * 16 + 4 * (e80 + 1) + 2 * half],
                          pf[nf * 16 + 4 * (e80 + 1) + 2 * half + 1]);
          auto r = __builtin_amdgcn_permlane32_swap((int)Y0, (int)Y1, false, false);
          paw[ks][half] = (u32)r[0];      // [Y0.lo, Y1.lo]
          paw[ks][2 + half] = (u32)r[1];  // [Y0.hi, Y1.hi]
        }
      }

      // ---- O^T += V^T P^T ----
      __builtin_amdgcn_s_setprio(1);
#pragma unroll
      for (int d2 = 0; d2 < 2; d2++) {
#pragma unroll
        for (int ks = 0; ks < 4; ks++) {
          int row = d2 * 32 + la;
          bf16x8 vf = *(const bf16x8*)&Vs[cur][row * 64 + (((ks * 2 + hi) ^ (row & 7)) << 3)];
          union { u32 w[4]; bf16x8 v; } pu;
          pu.w[0] = paw[ks][0]; pu.w[1] = paw[ks][1];
          pu.w[2] = paw[ks][2]; pu.w[3] = paw[ks][3];
          oacc[d2] = __builtin_amdgcn_mfma_f32_32x32x16_bf16(vf, pu.v, oacc[d2], 0, 0, 0);
        }
      }
      __builtin_amdgcn_s_setprio(0);
    }

    asm volatile("" ::: "memory");
    __builtin_amdgcn_s_barrier();
    asm volatile("" ::: "memory");
  }

  // ---- epilogue: O[q][d] = oacc^T / l ----
  const float inv = 1.0f / lrun;
  u16* Og = O + ((size_t)(b * S_LEN + q)) * EMB + h * HD;
#pragma unroll
  for (int d2 = 0; d2 < 2; d2++)
#pragma unroll
    for (int g = 0; g < 4; g++) {
      ushort4 ov;
      ov.x = f2bf(oacc[d2][g * 4 + 0] * inv);
      ov.y = f2bf(oacc[d2][g * 4 + 1] * inv);
      ov.z = f2bf(oacc[d2][g * 4 + 2] * inv);
      ov.w = f2bf(oacc[d2][g * 4 + 3] * inv);
      *(ushort4*)&Og[d2 * 32 + g * 8 + hi * 4] = ov;
    }
}

// ---------------- host ----------------

extern "C" void kernel_launch(void* const* d_in, const int* in_sizes, int n_in, void* d_out,
                              int out_size, void* d_ws, size_t ws_size, hipStream_t stream) {
  (void)in_sizes; (void)n_in; (void)out_size; (void)ws_size;
  const float* inq = (const float*)d_in[0];
  const float* inkv = (const float*)d_in[1];
  // d_in[2] = mask (causal tril, applied analytically)
  const float* Wq = (const float*)d_in[3];
  const float* Wk = (const float*)d_in[4];
  const float* Wv = (const float*)d_in[5];
  const float* Wo = (const float*)d_in[6];
  const float* rel = (const float*)d_in[7];
  float* out = (float*)d_out;

  char* ws = (char*)d_ws;
  size_t off = 0;
  auto alloc = [&](size_t bytes) {
    void* p = ws + off;
    off += (bytes + 255) & ~(size_t)255;
    return p;
  };
  u16* Aq = (u16*)alloc(16777216);    // inputs_q bf16 [8192][1024]
  u16* Akv = (u16*)alloc(16777216);   // inputs_kv bf16
  u16* Wqt = (u16*)alloc(2097152);    // Wq^T bf16 [N][K]
  u16* Wkt = (u16*)alloc(2097152);
  u16* Wvt = (u16*)alloc(2097152);
  u16* Wot = (u16*)alloc(2097152);
  u16* Qb = (u16*)alloc(16777216);    // Q bf16 [b][h][s][d], pre-scaled 1/8
  u16* Kb = (u16*)alloc(16777216);    // K bf16 [b][h][s][d]
  u16* Vtb = (u16*)alloc(16777216);   // V bf16 [b][h][d][s]
  u16* Ob = (u16*)alloc(16777216);    // attn out bf16 [b][s][h*64+d]
  float* btbl = (float*)alloc(131072);

  cvt_bf16<<<8192, 256, 0, stream>>>(inq, Aq, 2097152);
  cvt_bf16<<<8192, 256, 0, stream>>>(inkv, Akv, 2097152);
  transcvt<<<dim3(32, 32), 256, 0, stream>>>(Wq, Wqt);
  transcvt<<<dim3(32, 32), 256, 0, stream>>>(Wk, Wkt);
  transcvt<<<dim3(32, 32), 256, 0, stream>>>(Wv, Wvt);
  transcvt<<<dim3(32, 32), 256, 0, stream>>>(Wo, Wot);
  build_bias<<<128, 256, 0, stream>>>(rel, btbl);

  gemm_bf16<0><<<dim3(8, 64), 256, 0, stream>>>(Aq, Wqt, Qb, 0.125f);
  gemm_bf16<0><<<dim3(8, 64), 256, 0, stream>>>(Akv, Wkt, Kb, 1.0f);
  gemm_bf16<1><<<dim3(8, 64), 256, 0, stream>>>(Akv, Wvt, Vtb, 1.0f);
  attn_kernel<<<dim3(64, 16), 256, 0, stream>>>(Qb, Kb, Vtb, btbl, Ob);
  gemm_bf16<2><<<dim3(8, 64), 256, 0, stream>>>(Ob, Wot, out, 1.0f);
}